// Round 5
// baseline (300.997 us; speedup 1.0000x reference)
//
#include <hip/hip_runtime.h>
#include <hip/hip_bf16.h>
#include <stdint.h>

#define B_ 4
#define L_ 2048
#define H_ 8
#define E_ 64
#define ALPHA 0.1f
#define LOG2E 1.44269504088896f
// Q prescale: 1/sqrt(64) * log2(e) folded into projected Q so P = exp2(S)
#define QSCALE (0.125f * LOG2E)

typedef float f32x4 __attribute__((ext_vector_type(4)));
typedef short bf16x8 __attribute__((ext_vector_type(8)));
typedef short bf16x4 __attribute__((ext_vector_type(4)));
typedef uint32_t u32;
typedef unsigned short u16;
typedef u32 u32x2 __attribute__((ext_vector_type(2)));

__device__ __forceinline__ u16 f2bf(float f) {
    u32 x = __builtin_bit_cast(u32, f);
    u32 r = x + 0x7fffu + ((x >> 16) & 1u);   // round-to-nearest-even
    return (u16)(r >> 16);
}

// pack two positive floats to packed bf16 (round-half-up; P>0, never NaN)
__device__ __forceinline__ u32 pk2bf(float a, float b) {
    u32 ua = __builtin_bit_cast(u32, a) + 0x8000u;
    u32 ub = __builtin_bit_cast(u32, b) + 0x8000u;
    return (ua >> 16) | (ub & 0xffff0000u);
}

__device__ __forceinline__ f32x4 mfma16x16x16bf16(bf16x4 a, bf16x4 b, f32x4 c) {
#if __has_builtin(__builtin_amdgcn_mfma_f32_16x16x16bf16_1k)
    return __builtin_amdgcn_mfma_f32_16x16x16bf16_1k(a, b, c, 0, 0, 0);
#elif __has_builtin(__builtin_amdgcn_mfma_f32_16x16x16_bf16)
    return __builtin_amdgcn_mfma_f32_16x16x16_bf16(a, b, c, 0, 0, 0);
#else
    f32x4 d;
    asm volatile("v_mfma_f32_16x16x16_bf16 %0, %1, %2, %3"
                 : "=v"(d) : "v"(a), "v"(b), "v"(c));
    return d;
#endif
}

// ---------------------------------------------------------------------------
// Prep kernel (fused):
//  blocks [0,4096):   axis_aligned_projection Q,K  fp32 [B,L,H,E] -> bf16 [B*H,L,E]
//                     (Q additionally scaled by QSCALE = 0.125*log2e)
//  blocks [4096,5120): V transpose fp32 [B,S,H,D] -> bf16 Vt [B*H,D,S]
// ---------------------------------------------------------------------------
__global__ __launch_bounds__(256) void prep_kernel(const float* __restrict__ qin,
                                                   const float* __restrict__ kin,
                                                   const float* __restrict__ vin,
                                                   u16* __restrict__ qp,
                                                   u16* __restrict__ kp,
                                                   u16* __restrict__ vt) {
    __shared__ u16 tile[64][66];
    if (blockIdx.x < 4096) {
        const int RG = (B_ * L_ * H_) / 8;
        int wave = threadIdx.x >> 6, lane = threadIdx.x & 63;
        int g = blockIdx.x * 4 + wave;
        const float* src;
        u16* dst;
        int gr;
        float sc;
        if (g < RG) { src = qin; dst = qp; gr = g; sc = QSCALE; }
        else        { src = kin; dst = kp; gr = g - RG; sc = 1.0f; }

        int rig = lane >> 3;
        int c = (lane & 7) * 4;
        int row = gr * 8 + rig;

        const float* rp = src + (size_t)row * 64;
        float4 v0 = *(const float4*)(rp + c);
        float4 v1 = *(const float4*)(rp + c + 32);
        float f[8] = {v0.x, v0.y, v0.z, v0.w, v1.x, v1.y, v1.z, v1.w};

        float mx = 0.f;
#pragma unroll
        for (int i = 0; i < 8; ++i) mx = fmaxf(mx, fabsf(f[i]));
#pragma unroll
        for (int m = 1; m < 8; m <<= 1) mx = fmaxf(mx, __shfl_xor(mx, m));
        float thr = ALPHA * mx;

        u16 o[8];
#pragma unroll
        for (int i = 0; i < 8; ++i)
            o[i] = (fabsf(f[i]) >= thr) ? f2bf(f[i] * sc) : (u16)0;

        int b = row >> 14;
        int l = (row >> 3) & (L_ - 1);
        int h = row & 7;
        u16* orow = dst + ((size_t)(b * H_ + h) * L_ + l) * 64;
        uint2 p0 = {(u32)o[0] | ((u32)o[1] << 16), (u32)o[2] | ((u32)o[3] << 16)};
        uint2 p1 = {(u32)o[4] | ((u32)o[5] << 16), (u32)o[6] | ((u32)o[7] << 16)};
        *(uint2*)(orow + c) = p0;
        *(uint2*)(orow + c + 32) = p1;
    } else {
        int bx = blockIdx.x - 4096;
        int bh = bx >> 5, sblk = bx & 31;
        int b = bh >> 3, h = bh & 7;
        int t = threadIdx.x;
        int s0 = sblk * 64;

#pragma unroll
        for (int p = 0; p < 2; ++p) {
            int sl = p * 32 + (t >> 3);
            int c = (t & 7) * 4;
            const float* rp = vin + (((size_t)(b * L_ + s0 + sl)) * H_ + h) * 64;
            float4 a = *(const float4*)(rp + c);
            float4 bb = *(const float4*)(rp + c + 32);
            u32* d0 = (u32*)&tile[sl][c];
            d0[0] = (u32)f2bf(a.x) | ((u32)f2bf(a.y) << 16);
            d0[1] = (u32)f2bf(a.z) | ((u32)f2bf(a.w) << 16);
            u32* d1 = (u32*)&tile[sl][c + 32];
            d1[0] = (u32)f2bf(bb.x) | ((u32)f2bf(bb.y) << 16);
            d1[1] = (u32)f2bf(bb.z) | ((u32)f2bf(bb.w) << 16);
        }
        __syncthreads();
#pragma unroll
        for (int p = 0; p < 2; ++p) {
            int d = p * 32 + (t >> 3);
            int sc2 = (t & 7) * 8;
            u16 o[8];
#pragma unroll
            for (int i = 0; i < 8; ++i) o[i] = tile[sc2 + i][d];
            uint4 val;
            val.x = (u32)o[0] | ((u32)o[1] << 16);
            val.y = (u32)o[2] | ((u32)o[3] << 16);
            val.z = (u32)o[4] | ((u32)o[5] << 16);
            val.w = (u32)o[6] | ((u32)o[7] << 16);
            *(uint4*)(vt + ((size_t)bh * 64 + d) * L_ + s0 + sc2) = val;
        }
    }
}

// ---------------------------------------------------------------------------
// Flash attention, register-only P path (no LDS at all).
//   S^T subtile [16s x 16q] = mfma_16x16x32(A=K-frag, B=Q-frag):
//       C layout: q = lane&15, s = quad*4+r  == A-operand layout of 16x16x16
//   P = exp2(S) (scale*log2e folded into Q), packed to bf16 in-register.
//   PV: o[ni] = mfma_16x16x16(A=P, B=Vt 8-byte frag)  — O layout: d=lane&15,
//       q=quad*4+r (same as before).
// Grid: 1024 blocks = 32 qq-groups x 32 bh; 4 waves = q-tiles 4qq..4qq+3
// (uniform qq+1 key-tiles per wave). qq interleaved so each CU's 4 resident
// blocks sum to 66 tile-units. Diagonal tile: skip fully-masked subtiles.
// ---------------------------------------------------------------------------
__global__ __launch_bounds__(256, 4) void flash_kernel(const u16* __restrict__ Qp,
                                                       const u16* __restrict__ Kp,
                                                       const u16* __restrict__ Vt,
                                                       float* __restrict__ out) {
    int wave = threadIdx.x >> 6, lane = threadIdx.x & 63;
    int bh = blockIdx.x & 31;
    int r5 = blockIdx.x >> 5;            // 0..31
    int g = r5 & 7, kr = r5 >> 3;
    // per-CU-balanced interleave: sums of (qq+1) over the 4 rounds = 66 for all g
    int qq = (kr == 0) ? (31 - g) : (kr == 1) ? (16 + g) : (kr == 2) ? (15 - g) : g;
    int lo = lane & 15, quad = lane >> 4;
    int q0 = qq * 64 + wave * 16;
    int b = bh >> 3, h = bh & 7;

    const u16* kbase = Kp + (size_t)bh * L_ * 64;
    const u16* vbase = Vt + (size_t)bh * 64 * L_;

    // Q fragment (B-operand of the S^T MFMA; same registers as A-layout)
    const u16* qbase = Qp + ((size_t)bh * L_ + q0 + lo) * 64 + quad * 8;
    bf16x8 aQ0 = *(const bf16x8*)(qbase);
    bf16x8 aQ1 = *(const bf16x8*)(qbase + 32);

    f32x4 o[4];
#pragma unroll
    for (int ni = 0; ni < 4; ++ni) o[ni] = (f32x4){0.f, 0.f, 0.f, 0.f};
    float ls = 0.f;   // per-lane partial of l[q = q0+lo] (over this quad's s-slices)

    // ---- full tiles 0..qq-1 ----
    for (int kt = 0; kt < qq; ++kt) {
        int sb = kt << 6;
        bf16x8 kb0[4], kb1[4];
#pragma unroll
        for (int sub = 0; sub < 4; ++sub) {
            const u16* kb = kbase + ((size_t)(sb + sub * 16 + lo)) * 64 + quad * 8;
            kb0[sub] = *(const bf16x8*)kb;
            kb1[sub] = *(const bf16x8*)(kb + 32);
        }
#pragma unroll
        for (int sub = 0; sub < 4; ++sub) {
            int sbase = sb + sub * 16;
            f32x4 S = {0.f, 0.f, 0.f, 0.f};
            S = __builtin_amdgcn_mfma_f32_16x16x32_bf16(kb0[sub], aQ0, S, 0, 0, 0);
            S = __builtin_amdgcn_mfma_f32_16x16x32_bf16(kb1[sub], aQ1, S, 0, 0, 0);

            bf16x4 vf[4];
#pragma unroll
            for (int ni = 0; ni < 4; ++ni)
                vf[ni] = *(const bf16x4*)(vbase + ((size_t)(ni * 16 + lo)) * L_ +
                                          sbase + quad * 4);

            float P0 = __builtin_amdgcn_exp2f(S[0]);
            float P1 = __builtin_amdgcn_exp2f(S[1]);
            float P2 = __builtin_amdgcn_exp2f(S[2]);
            float P3 = __builtin_amdgcn_exp2f(S[3]);
            ls += (P0 + P1) + (P2 + P3);
            u32x2 pk = {pk2bf(P0, P1), pk2bf(P2, P3)};
            bf16x4 aP = __builtin_bit_cast(bf16x4, pk);

#pragma unroll
            for (int ni = 0; ni < 4; ++ni)
                o[ni] = mfma16x16x16bf16(aP, vf[ni], o[ni]);
        }
    }

    // ---- diagonal tile qq: subtiles 0..wave (sub>wave fully masked -> skip) ----
    {
        int sb = qq << 6;
        for (int sub = 0; sub <= wave; ++sub) {
            int sbase = sb + sub * 16;
            const u16* kb = kbase + ((size_t)(sbase + lo)) * 64 + quad * 8;
            bf16x8 k0 = *(const bf16x8*)kb;
            bf16x8 k1 = *(const bf16x8*)(kb + 32);
            f32x4 S = {0.f, 0.f, 0.f, 0.f};
            S = __builtin_amdgcn_mfma_f32_16x16x32_bf16(k0, aQ0, S, 0, 0, 0);
            S = __builtin_amdgcn_mfma_f32_16x16x32_bf16(k1, aQ1, S, 0, 0, 0);

            bf16x4 vf[4];
#pragma unroll
            for (int ni = 0; ni < 4; ++ni)
                vf[ni] = *(const bf16x4*)(vbase + ((size_t)(ni * 16 + lo)) * L_ +
                                          sbase + quad * 4);

            float P[4];
            if (sub < wave) {
#pragma unroll
                for (int r = 0; r < 4; ++r) P[r] = __builtin_amdgcn_exp2f(S[r]);
            } else {
                int q = q0 + lo;
#pragma unroll
                for (int r = 0; r < 4; ++r) {
                    float e = __builtin_amdgcn_exp2f(S[r]);
                    P[r] = (sbase + quad * 4 + r > q) ? 0.f : e;
                }
            }
            ls += (P[0] + P[1]) + (P[2] + P[3]);
            u32x2 pk = {pk2bf(P[0], P[1]), pk2bf(P[2], P[3])};
            bf16x4 aP = __builtin_bit_cast(bf16x4, pk);
#pragma unroll
            for (int ni = 0; ni < 4; ++ni)
                o[ni] = mfma16x16x16bf16(aP, vf[ni], o[ni]);
        }
    }

    // ---- epilogue ----
    // full l[q=q0+lo] on every lane:
    ls += __shfl_xor(ls, 16);
    ls += __shfl_xor(ls, 32);
#pragma unroll
    for (int r = 0; r < 4; ++r) {
        float lr = __shfl(ls, quad * 4 + r);   // l for output row q0+quad*4+r
        float inv = 1.0f / lr;
        int q = q0 + quad * 4 + r;
        float* ob = out + (((size_t)(b * L_ + q)) * H_ + h) * 64 + lo;
        ob[0]  = o[0][r] * inv;
        ob[16] = o[1][r] * inv;
        ob[32] = o[2][r] * inv;
        ob[48] = o[3][r] * inv;
    }
}

extern "C" void kernel_launch(void* const* d_in, const int* in_sizes, int n_in,
                              void* d_out, int out_size, void* d_ws, size_t ws_size,
                              hipStream_t stream) {
    const float* q = (const float*)d_in[0];
    const float* k = (const float*)d_in[1];
    const float* v = (const float*)d_in[2];
    // d_in[3] = attn_mask: deterministic causal, recomputed analytically.
    float* out = (float*)d_out;

    const size_t TSZ = (size_t)B_ * H_ * L_ * 64;
    u16* qp = (u16*)d_ws;
    u16* kp = qp + TSZ;
    u16* vt = kp + TSZ;

    prep_kernel<<<5120, 256, 0, stream>>>(q, k, v, qp, kp, vt);
    flash_kernel<<<1024, 256, 0, stream>>>(qp, kp, vt, out);
}

// Round 6
// 210.035 us; speedup vs baseline: 1.4331x; 1.4331x over previous
//
#include <hip/hip_runtime.h>
#include <hip/hip_bf16.h>
#include <stdint.h>

#define B_ 4
#define L_ 2048
#define H_ 8
#define E_ 64
#define ALPHA 0.1f
#define LOG2E 1.44269504088896f
// Q prescale: 1/sqrt(64) * log2(e) folded into projected Q so P = exp2(S)
#define QSCALE (0.125f * LOG2E)
#define TSTR 72   // LDS tile row stride (elements): 144B rows -> b128 reads at conflict floor

typedef float f32x4 __attribute__((ext_vector_type(4)));
typedef short bf16x8 __attribute__((ext_vector_type(8)));
typedef short bf16x4 __attribute__((ext_vector_type(4)));
typedef uint32_t u32;
typedef unsigned short u16;
typedef u32 u32x2 __attribute__((ext_vector_type(2)));

__device__ __forceinline__ u16 f2bf(float f) {
    u32 x = __builtin_bit_cast(u32, f);
    u32 r = x + 0x7fffu + ((x >> 16) & 1u);   // round-to-nearest-even
    return (u16)(r >> 16);
}

// pack two positive floats to packed bf16 (round-half-up; P>0, never NaN)
__device__ __forceinline__ u32 pk2bf(float a, float b) {
    u32 ua = __builtin_bit_cast(u32, a) + 0x8000u;
    u32 ub = __builtin_bit_cast(u32, b) + 0x8000u;
    return (ua >> 16) | (ub & 0xffff0000u);
}

__device__ __forceinline__ f32x4 mfma16x16x16bf16(bf16x4 a, bf16x4 b, f32x4 c) {
#if __has_builtin(__builtin_amdgcn_mfma_f32_16x16x16bf16_1k)
    return __builtin_amdgcn_mfma_f32_16x16x16bf16_1k(a, b, c, 0, 0, 0);
#elif __has_builtin(__builtin_amdgcn_mfma_f32_16x16x16_bf16)
    return __builtin_amdgcn_mfma_f32_16x16x16_bf16(a, b, c, 0, 0, 0);
#else
    f32x4 d;
    asm volatile("v_mfma_f32_16x16x16_bf16 %0, %1, %2, %3"
                 : "=v"(d) : "v"(a), "v"(b), "v"(c));
    return d;
#endif
}

// ---------------------------------------------------------------------------
// Prep kernel (fused): projection Q,K -> bf16 [B*H,L,E]; V transpose -> bf16
// Vt [B*H,D,S]. (unchanged from round 5)
// ---------------------------------------------------------------------------
__global__ __launch_bounds__(256) void prep_kernel(const float* __restrict__ qin,
                                                   const float* __restrict__ kin,
                                                   const float* __restrict__ vin,
                                                   u16* __restrict__ qp,
                                                   u16* __restrict__ kp,
                                                   u16* __restrict__ vt) {
    __shared__ u16 tile[64][66];
    if (blockIdx.x < 4096) {
        const int RG = (B_ * L_ * H_) / 8;
        int wave = threadIdx.x >> 6, lane = threadIdx.x & 63;
        int g = blockIdx.x * 4 + wave;
        const float* src;
        u16* dst;
        int gr;
        float sc;
        if (g < RG) { src = qin; dst = qp; gr = g; sc = QSCALE; }
        else        { src = kin; dst = kp; gr = g - RG; sc = 1.0f; }

        int rig = lane >> 3;
        int c = (lane & 7) * 4;
        int row = gr * 8 + rig;

        const float* rp = src + (size_t)row * 64;
        float4 v0 = *(const float4*)(rp + c);
        float4 v1 = *(const float4*)(rp + c + 32);
        float f[8] = {v0.x, v0.y, v0.z, v0.w, v1.x, v1.y, v1.z, v1.w};

        float mx = 0.f;
#pragma unroll
        for (int i = 0; i < 8; ++i) mx = fmaxf(mx, fabsf(f[i]));
#pragma unroll
        for (int m = 1; m < 8; m <<= 1) mx = fmaxf(mx, __shfl_xor(mx, m));
        float thr = ALPHA * mx;

        u16 o[8];
#pragma unroll
        for (int i = 0; i < 8; ++i)
            o[i] = (fabsf(f[i]) >= thr) ? f2bf(f[i] * sc) : (u16)0;

        int b = row >> 14;
        int l = (row >> 3) & (L_ - 1);
        int h = row & 7;
        u16* orow = dst + ((size_t)(b * H_ + h) * L_ + l) * 64;
        uint2 p0 = {(u32)o[0] | ((u32)o[1] << 16), (u32)o[2] | ((u32)o[3] << 16)};
        uint2 p1 = {(u32)o[4] | ((u32)o[5] << 16), (u32)o[6] | ((u32)o[7] << 16)};
        *(uint2*)(orow + c) = p0;
        *(uint2*)(orow + c + 32) = p1;
    } else {
        int bx = blockIdx.x - 4096;
        int bh = bx >> 5, sblk = bx & 31;
        int b = bh >> 3, h = bh & 7;
        int t = threadIdx.x;
        int s0 = sblk * 64;

#pragma unroll
        for (int p = 0; p < 2; ++p) {
            int sl = p * 32 + (t >> 3);
            int c = (t & 7) * 4;
            const float* rp = vin + (((size_t)(b * L_ + s0 + sl)) * H_ + h) * 64;
            float4 a = *(const float4*)(rp + c);
            float4 bb = *(const float4*)(rp + c + 32);
            u32* d0 = (u32*)&tile[sl][c];
            d0[0] = (u32)f2bf(a.x) | ((u32)f2bf(a.y) << 16);
            d0[1] = (u32)f2bf(a.z) | ((u32)f2bf(a.w) << 16);
            u32* d1 = (u32*)&tile[sl][c + 32];
            d1[0] = (u32)f2bf(bb.x) | ((u32)f2bf(bb.y) << 16);
            d1[1] = (u32)f2bf(bb.z) | ((u32)f2bf(bb.w) << 16);
        }
        __syncthreads();
#pragma unroll
        for (int p = 0; p < 2; ++p) {
            int d = p * 32 + (t >> 3);
            int sc2 = (t & 7) * 8;
            u16 o[8];
#pragma unroll
            for (int i = 0; i < 8; ++i) o[i] = tile[sc2 + i][d];
            uint4 val;
            val.x = (u32)o[0] | ((u32)o[1] << 16);
            val.y = (u32)o[2] | ((u32)o[3] << 16);
            val.z = (u32)o[4] | ((u32)o[5] << 16);
            val.w = (u32)o[6] | ((u32)o[7] << 16);
            *(uint4*)(vt + ((size_t)bh * 64 + d) * L_ + s0 + sc2) = val;
        }
    }
}

// ---------------------------------------------------------------------------
// Flash attention v6: block-cooperative double-buffered LDS staging of K & Vt
// tiles (shared by the 4 waves), register-only P path (verified R5).
//   S^T subtile: mfma_16x16x32(A=K-frag from LDS, B=Q-frag) -> C: q=lane&15,
//   s=quad*4+r == A-layout of 16x16x16. P=exp2(S) packed in-register.
//   PV: mfma_16x16x16(A=P, B=Vt-frag from LDS).
// Grid: 1024 = 32 qq x 32 bh; wave w owns q-tile 4qq+w; all waves run tiles
// 0..qq (uniform barrier count). Tile kt+2 global->VGPR loads issued one full
// iteration before their ds_write; one __syncthreads per tile.
// ---------------------------------------------------------------------------
__global__ __launch_bounds__(256, 4) void flash_kernel(const u16* __restrict__ Qp,
                                                       const u16* __restrict__ Kp,
                                                       const u16* __restrict__ Vt,
                                                       float* __restrict__ out) {
    __shared__ u16 kbuf[2][64 * TSTR];   // 2 x 9216 B
    __shared__ u16 vbuf[2][64 * TSTR];   // 2 x 9216 B
    int t = threadIdx.x;
    int wave = t >> 6, lane = t & 63;
    int bh = blockIdx.x & 31;
    int r5 = blockIdx.x >> 5;
    int g = r5 & 7, kr = r5 >> 3;
    // per-CU-balanced interleave: sums of (qq+1) over the 4 rounds = 66 for all g
    int qq = (kr == 0) ? (31 - g) : (kr == 1) ? (16 + g) : (kr == 2) ? (15 - g) : g;
    int lo = lane & 15, quad = lane >> 4;
    int q0 = qq * 64 + wave * 16;
    int b = bh >> 3, h = bh & 7;

    const u16* kbase = Kp + (size_t)bh * L_ * 64;
    const u16* vbase = Vt + (size_t)bh * 64 * L_;

    // staging indices: thread stages rows r0 and r0+32, 16B chunk ch
    int r0 = t >> 3;          // 0..31
    int ch = t & 7;           // 0..7

    // Q fragment (B-operand of the S^T MFMA)
    const u16* qbase = Qp + ((size_t)bh * L_ + q0 + lo) * 64 + quad * 8;
    bf16x8 aQ0 = *(const bf16x8*)(qbase);
    bf16x8 aQ1 = *(const bf16x8*)(qbase + 32);

    f32x4 o[4];
#pragma unroll
    for (int ni = 0; ni < 4; ++ni) o[ni] = (f32x4){0.f, 0.f, 0.f, 0.f};
    float ls = 0.f;   // per-lane partial of l[q=q0+lo]

    uint4 kreg[2], vreg[2];
    // ---- prologue: tile 0 -> LDS buf0; issue tile 1 loads ----
    kreg[0] = *(const uint4*)(kbase + (size_t)t * 8);            // K tile contiguous 8KB
    kreg[1] = *(const uint4*)(kbase + (size_t)(256 + t) * 8);
    vreg[0] = *(const uint4*)(vbase + (size_t)r0 * L_ + ch * 8);
    vreg[1] = *(const uint4*)(vbase + (size_t)(r0 + 32) * L_ + ch * 8);
    *(uint4*)(&kbuf[0][r0 * TSTR + ch * 8]) = kreg[0];
    *(uint4*)(&kbuf[0][(r0 + 32) * TSTR + ch * 8]) = kreg[1];
    *(uint4*)(&vbuf[0][r0 * TSTR + ch * 8]) = vreg[0];
    *(uint4*)(&vbuf[0][(r0 + 32) * TSTR + ch * 8]) = vreg[1];
    if (qq > 0) {
        kreg[0] = *(const uint4*)(kbase + (size_t)64 * 64 + t * 8);
        kreg[1] = *(const uint4*)(kbase + (size_t)64 * 64 + (256 + t) * 8);
        vreg[0] = *(const uint4*)(vbase + (size_t)r0 * L_ + 64 + ch * 8);
        vreg[1] = *(const uint4*)(vbase + (size_t)(r0 + 32) * L_ + 64 + ch * 8);
    }
    __syncthreads();

    for (int kt = 0; kt <= qq; ++kt) {
        int cur = kt & 1;
        // ---- stage tile kt+1 into the idle buffer; issue tile kt+2 loads ----
        if (kt < qq) {
            u16* kd = kbuf[cur ^ 1];
            u16* vd = vbuf[cur ^ 1];
            *(uint4*)(&kd[r0 * TSTR + ch * 8]) = kreg[0];
            *(uint4*)(&kd[(r0 + 32) * TSTR + ch * 8]) = kreg[1];
            *(uint4*)(&vd[r0 * TSTR + ch * 8]) = vreg[0];
            *(uint4*)(&vd[(r0 + 32) * TSTR + ch * 8]) = vreg[1];
            if (kt + 1 < qq) {
                size_t sb2 = (size_t)(kt + 2) << 6;
                kreg[0] = *(const uint4*)(kbase + sb2 * 64 + t * 8);
                kreg[1] = *(const uint4*)(kbase + sb2 * 64 + (256 + t) * 8);
                vreg[0] = *(const uint4*)(vbase + (size_t)r0 * L_ + sb2 + ch * 8);
                vreg[1] = *(const uint4*)(vbase + (size_t)(r0 + 32) * L_ + sb2 + ch * 8);
            }
        }

        const u16* ks = kbuf[cur];
        const u16* vs = vbuf[cur];

        auto body = [&](int sub, bool diag) {
            bf16x8 k0 = *(const bf16x8*)(ks + (sub * 16 + lo) * TSTR + quad * 8);
            bf16x8 k1 = *(const bf16x8*)(ks + (sub * 16 + lo) * TSTR + 32 + quad * 8);
            f32x4 S = {0.f, 0.f, 0.f, 0.f};
            S = __builtin_amdgcn_mfma_f32_16x16x32_bf16(k0, aQ0, S, 0, 0, 0);
            S = __builtin_amdgcn_mfma_f32_16x16x32_bf16(k1, aQ1, S, 0, 0, 0);

            bf16x4 vf[4];
#pragma unroll
            for (int ni = 0; ni < 4; ++ni)
                vf[ni] = *(const bf16x4*)(vs + (ni * 16 + lo) * TSTR + sub * 16 + quad * 4);

            float P[4];
            if (!diag) {
#pragma unroll
                for (int r = 0; r < 4; ++r) P[r] = __builtin_amdgcn_exp2f(S[r]);
            } else {
                int q = q0 + lo;
                int sbase = (kt << 6) + sub * 16 + quad * 4;
#pragma unroll
                for (int r = 0; r < 4; ++r) {
                    float e = __builtin_amdgcn_exp2f(S[r]);
                    P[r] = (sbase + r > q) ? 0.f : e;
                }
            }
            ls += (P[0] + P[1]) + (P[2] + P[3]);
            u32x2 pk = {pk2bf(P[0], P[1]), pk2bf(P[2], P[3])};
            bf16x4 aP = __builtin_bit_cast(bf16x4, pk);
#pragma unroll
            for (int ni = 0; ni < 4; ++ni)
                o[ni] = mfma16x16x16bf16(aP, vf[ni], o[ni]);
        };

        if (kt < qq) {
#pragma unroll
            for (int sub = 0; sub < 4; ++sub) body(sub, false);
        } else {
            // diagonal tile: subtiles > wave are fully masked -> skip
            for (int sub = 0; sub < wave; ++sub) body(sub, false);
            body(wave, true);
        }
        __syncthreads();
    }

    // ---- epilogue: full l on every lane, normalize, store fp32 ----
    ls += __shfl_xor(ls, 16);
    ls += __shfl_xor(ls, 32);
#pragma unroll
    for (int r = 0; r < 4; ++r) {
        float lr = __shfl(ls, quad * 4 + r);   // l for output row q0+quad*4+r
        float inv = 1.0f / lr;
        int q = q0 + quad * 4 + r;
        float* ob = out + (((size_t)(b * L_ + q)) * H_ + h) * 64 + lo;
        ob[0]  = o[0][r] * inv;
        ob[16] = o[1][r] * inv;
        ob[32] = o[2][r] * inv;
        ob[48] = o[3][r] * inv;
    }
}

extern "C" void kernel_launch(void* const* d_in, const int* in_sizes, int n_in,
                              void* d_out, int out_size, void* d_ws, size_t ws_size,
                              hipStream_t stream) {
    const float* q = (const float*)d_in[0];
    const float* k = (const float*)d_in[1];
    const float* v = (const float*)d_in[2];
    // d_in[3] = attn_mask: deterministic causal, recomputed analytically.
    float* out = (float*)d_out;

    const size_t TSZ = (size_t)B_ * H_ * L_ * 64;
    u16* qp = (u16*)d_ws;
    u16* kp = qp + TSZ;
    u16* vt = kp + TSZ;

    prep_kernel<<<5120, 256, 0, stream>>>(q, k, v, qp, kp, vt);
    flash_kernel<<<1024, 256, 0, stream>>>(qp, kp, vt, out);
}

// Round 7
// 208.216 us; speedup vs baseline: 1.4456x; 1.0087x over previous
//
#include <hip/hip_runtime.h>
#include <hip/hip_bf16.h>
#include <stdint.h>

#define B_ 4
#define L_ 2048
#define H_ 8
#define E_ 64
#define ALPHA 0.1f
#define LOG2E 1.44269504088896f
// Q prescale: 1/sqrt(64) * log2(e) folded into projected Q so P = exp2(S)
#define QSCALE (0.125f * LOG2E)
#define TSTR 72   // LDS tile row stride (elements): 144B rows -> b128 reads at conflict floor

typedef float f32x4 __attribute__((ext_vector_type(4)));
typedef short bf16x8 __attribute__((ext_vector_type(8)));
typedef short bf16x4 __attribute__((ext_vector_type(4)));
typedef uint32_t u32;
typedef unsigned short u16;
typedef u32 u32x2 __attribute__((ext_vector_type(2)));

// Workgroup barrier WITHOUT the vmcnt(0) drain __syncthreads() emits.
// Safe here because the only cross-wave shared state is LDS (drained via
// lgkmcnt(0)); in-flight global loads target per-thread VGPRs and the
// compiler inserts vmcnt waits before their first use (the ds_write).
__device__ __forceinline__ void barrier_lds_only() {
    asm volatile("s_waitcnt lgkmcnt(0)\n\ts_barrier" ::: "memory");
}

__device__ __forceinline__ u16 f2bf(float f) {
    u32 x = __builtin_bit_cast(u32, f);
    u32 r = x + 0x7fffu + ((x >> 16) & 1u);   // round-to-nearest-even
    return (u16)(r >> 16);
}

// pack two positive floats to packed bf16 (round-half-up; P>0, never NaN)
__device__ __forceinline__ u32 pk2bf(float a, float b) {
    u32 ua = __builtin_bit_cast(u32, a) + 0x8000u;
    u32 ub = __builtin_bit_cast(u32, b) + 0x8000u;
    return (ua >> 16) | (ub & 0xffff0000u);
}

__device__ __forceinline__ f32x4 mfma16x16x16bf16(bf16x4 a, bf16x4 b, f32x4 c) {
#if __has_builtin(__builtin_amdgcn_mfma_f32_16x16x16bf16_1k)
    return __builtin_amdgcn_mfma_f32_16x16x16bf16_1k(a, b, c, 0, 0, 0);
#elif __has_builtin(__builtin_amdgcn_mfma_f32_16x16x16_bf16)
    return __builtin_amdgcn_mfma_f32_16x16x16_bf16(a, b, c, 0, 0, 0);
#else
    f32x4 d;
    asm volatile("v_mfma_f32_16x16x16_bf16 %0, %1, %2, %3"
                 : "=v"(d) : "v"(a), "v"(b), "v"(c));
    return d;
#endif
}

// ---------------------------------------------------------------------------
// Prep kernel (fused): projection Q,K -> bf16 [B*H,L,E]; V transpose -> bf16
// Vt [B*H,D,S]. (unchanged from round 6)
// ---------------------------------------------------------------------------
__global__ __launch_bounds__(256) void prep_kernel(const float* __restrict__ qin,
                                                   const float* __restrict__ kin,
                                                   const float* __restrict__ vin,
                                                   u16* __restrict__ qp,
                                                   u16* __restrict__ kp,
                                                   u16* __restrict__ vt) {
    __shared__ u16 tile[64][66];
    if (blockIdx.x < 4096) {
        const int RG = (B_ * L_ * H_) / 8;
        int wave = threadIdx.x >> 6, lane = threadIdx.x & 63;
        int g = blockIdx.x * 4 + wave;
        const float* src;
        u16* dst;
        int gr;
        float sc;
        if (g < RG) { src = qin; dst = qp; gr = g; sc = QSCALE; }
        else        { src = kin; dst = kp; gr = g - RG; sc = 1.0f; }

        int rig = lane >> 3;
        int c = (lane & 7) * 4;
        int row = gr * 8 + rig;

        const float* rp = src + (size_t)row * 64;
        float4 v0 = *(const float4*)(rp + c);
        float4 v1 = *(const float4*)(rp + c + 32);
        float f[8] = {v0.x, v0.y, v0.z, v0.w, v1.x, v1.y, v1.z, v1.w};

        float mx = 0.f;
#pragma unroll
        for (int i = 0; i < 8; ++i) mx = fmaxf(mx, fabsf(f[i]));
#pragma unroll
        for (int m = 1; m < 8; m <<= 1) mx = fmaxf(mx, __shfl_xor(mx, m));
        float thr = ALPHA * mx;

        u16 o[8];
#pragma unroll
        for (int i = 0; i < 8; ++i)
            o[i] = (fabsf(f[i]) >= thr) ? f2bf(f[i] * sc) : (u16)0;

        int b = row >> 14;
        int l = (row >> 3) & (L_ - 1);
        int h = row & 7;
        u16* orow = dst + ((size_t)(b * H_ + h) * L_ + l) * 64;
        uint2 p0 = {(u32)o[0] | ((u32)o[1] << 16), (u32)o[2] | ((u32)o[3] << 16)};
        uint2 p1 = {(u32)o[4] | ((u32)o[5] << 16), (u32)o[6] | ((u32)o[7] << 16)};
        *(uint2*)(orow + c) = p0;
        *(uint2*)(orow + c + 32) = p1;
    } else {
        int bx = blockIdx.x - 4096;
        int bh = bx >> 5, sblk = bx & 31;
        int b = bh >> 3, h = bh & 7;
        int t = threadIdx.x;
        int s0 = sblk * 64;

#pragma unroll
        for (int p = 0; p < 2; ++p) {
            int sl = p * 32 + (t >> 3);
            int c = (t & 7) * 4;
            const float* rp = vin + (((size_t)(b * L_ + s0 + sl)) * H_ + h) * 64;
            float4 a = *(const float4*)(rp + c);
            float4 bb = *(const float4*)(rp + c + 32);
            u32* d0 = (u32*)&tile[sl][c];
            d0[0] = (u32)f2bf(a.x) | ((u32)f2bf(a.y) << 16);
            d0[1] = (u32)f2bf(a.z) | ((u32)f2bf(a.w) << 16);
            u32* d1 = (u32*)&tile[sl][c + 32];
            d1[0] = (u32)f2bf(bb.x) | ((u32)f2bf(bb.y) << 16);
            d1[1] = (u32)f2bf(bb.z) | ((u32)f2bf(bb.w) << 16);
        }
        __syncthreads();
#pragma unroll
        for (int p = 0; p < 2; ++p) {
            int d = p * 32 + (t >> 3);
            int sc2 = (t & 7) * 8;
            u16 o[8];
#pragma unroll
            for (int i = 0; i < 8; ++i) o[i] = tile[sc2 + i][d];
            uint4 val;
            val.x = (u32)o[0] | ((u32)o[1] << 16);
            val.y = (u32)o[2] | ((u32)o[3] << 16);
            val.z = (u32)o[4] | ((u32)o[5] << 16);
            val.w = (u32)o[6] | ((u32)o[7] << 16);
            *(uint4*)(vt + ((size_t)bh * 64 + d) * L_ + s0 + sc2) = val;
        }
    }
}

// ---------------------------------------------------------------------------
// Flash attention v7: identical to v6 except the per-tile barrier is
// lgkmcnt-only (no vmcnt drain), so the kt+2 global prefetch genuinely stays
// in flight across tiles (the CDNA analog of cp.async.wait_group N).
// ---------------------------------------------------------------------------
__global__ __launch_bounds__(256, 4) void flash_kernel(const u16* __restrict__ Qp,
                                                       const u16* __restrict__ Kp,
                                                       const u16* __restrict__ Vt,
                                                       float* __restrict__ out) {
    __shared__ u16 kbuf[2][64 * TSTR];   // 2 x 9216 B
    __shared__ u16 vbuf[2][64 * TSTR];   // 2 x 9216 B
    int t = threadIdx.x;
    int wave = t >> 6, lane = t & 63;
    int bh = blockIdx.x & 31;
    int r5 = blockIdx.x >> 5;
    int g = r5 & 7, kr = r5 >> 3;
    // per-CU-balanced interleave: sums of (qq+1) over the 4 rounds = 66 for all g
    int qq = (kr == 0) ? (31 - g) : (kr == 1) ? (16 + g) : (kr == 2) ? (15 - g) : g;
    int lo = lane & 15, quad = lane >> 4;
    int q0 = qq * 64 + wave * 16;
    int b = bh >> 3, h = bh & 7;

    const u16* kbase = Kp + (size_t)bh * L_ * 64;
    const u16* vbase = Vt + (size_t)bh * 64 * L_;

    // staging indices: thread stages rows r0 and r0+32, 16B chunk ch
    int r0 = t >> 3;          // 0..31
    int ch = t & 7;           // 0..7

    // Q fragment (B-operand of the S^T MFMA)
    const u16* qbase = Qp + ((size_t)bh * L_ + q0 + lo) * 64 + quad * 8;
    bf16x8 aQ0 = *(const bf16x8*)(qbase);
    bf16x8 aQ1 = *(const bf16x8*)(qbase + 32);

    f32x4 o[4];
#pragma unroll
    for (int ni = 0; ni < 4; ++ni) o[ni] = (f32x4){0.f, 0.f, 0.f, 0.f};
    float ls = 0.f;   // per-lane partial of l[q=q0+lo]

    uint4 kreg[2], vreg[2];
    // ---- prologue: tile 0 -> LDS buf0; issue tile 1 loads ----
    kreg[0] = *(const uint4*)(kbase + (size_t)t * 8);            // K tile contiguous 8KB
    kreg[1] = *(const uint4*)(kbase + (size_t)(256 + t) * 8);
    vreg[0] = *(const uint4*)(vbase + (size_t)r0 * L_ + ch * 8);
    vreg[1] = *(const uint4*)(vbase + (size_t)(r0 + 32) * L_ + ch * 8);
    *(uint4*)(&kbuf[0][r0 * TSTR + ch * 8]) = kreg[0];
    *(uint4*)(&kbuf[0][(r0 + 32) * TSTR + ch * 8]) = kreg[1];
    *(uint4*)(&vbuf[0][r0 * TSTR + ch * 8]) = vreg[0];
    *(uint4*)(&vbuf[0][(r0 + 32) * TSTR + ch * 8]) = vreg[1];
    if (qq > 0) {
        kreg[0] = *(const uint4*)(kbase + (size_t)64 * 64 + t * 8);
        kreg[1] = *(const uint4*)(kbase + (size_t)64 * 64 + (256 + t) * 8);
        vreg[0] = *(const uint4*)(vbase + (size_t)r0 * L_ + 64 + ch * 8);
        vreg[1] = *(const uint4*)(vbase + (size_t)(r0 + 32) * L_ + 64 + ch * 8);
    }
    barrier_lds_only();

    for (int kt = 0; kt <= qq; ++kt) {
        int cur = kt & 1;
        // ---- stage tile kt+1 into the idle buffer; issue tile kt+2 loads ----
        if (kt < qq) {
            u16* kd = kbuf[cur ^ 1];
            u16* vd = vbuf[cur ^ 1];
            *(uint4*)(&kd[r0 * TSTR + ch * 8]) = kreg[0];
            *(uint4*)(&kd[(r0 + 32) * TSTR + ch * 8]) = kreg[1];
            *(uint4*)(&vd[r0 * TSTR + ch * 8]) = vreg[0];
            *(uint4*)(&vd[(r0 + 32) * TSTR + ch * 8]) = vreg[1];
            if (kt + 1 < qq) {
                size_t sb2 = (size_t)(kt + 2) << 6;
                kreg[0] = *(const uint4*)(kbase + sb2 * 64 + t * 8);
                kreg[1] = *(const uint4*)(kbase + sb2 * 64 + (256 + t) * 8);
                vreg[0] = *(const uint4*)(vbase + (size_t)r0 * L_ + sb2 + ch * 8);
                vreg[1] = *(const uint4*)(vbase + (size_t)(r0 + 32) * L_ + sb2 + ch * 8);
            }
        }

        const u16* ks = kbuf[cur];
        const u16* vs = vbuf[cur];

        auto body = [&](int sub, bool diag) {
            bf16x8 k0 = *(const bf16x8*)(ks + (sub * 16 + lo) * TSTR + quad * 8);
            bf16x8 k1 = *(const bf16x8*)(ks + (sub * 16 + lo) * TSTR + 32 + quad * 8);
            f32x4 S = {0.f, 0.f, 0.f, 0.f};
            S = __builtin_amdgcn_mfma_f32_16x16x32_bf16(k0, aQ0, S, 0, 0, 0);
            S = __builtin_amdgcn_mfma_f32_16x16x32_bf16(k1, aQ1, S, 0, 0, 0);

            bf16x4 vf[4];
#pragma unroll
            for (int ni = 0; ni < 4; ++ni)
                vf[ni] = *(const bf16x4*)(vs + (ni * 16 + lo) * TSTR + sub * 16 + quad * 4);

            float P[4];
            if (!diag) {
#pragma unroll
                for (int r = 0; r < 4; ++r) P[r] = __builtin_amdgcn_exp2f(S[r]);
            } else {
                int q = q0 + lo;
                int sbase = (kt << 6) + sub * 16 + quad * 4;
#pragma unroll
                for (int r = 0; r < 4; ++r) {
                    float e = __builtin_amdgcn_exp2f(S[r]);
                    P[r] = (sbase + r > q) ? 0.f : e;
                }
            }
            ls += (P[0] + P[1]) + (P[2] + P[3]);
            u32x2 pk = {pk2bf(P[0], P[1]), pk2bf(P[2], P[3])};
            bf16x4 aP = __builtin_bit_cast(bf16x4, pk);
#pragma unroll
            for (int ni = 0; ni < 4; ++ni)
                o[ni] = mfma16x16x16bf16(aP, vf[ni], o[ni]);
        };

        if (kt < qq) {
#pragma unroll
            for (int sub = 0; sub < 4; ++sub) body(sub, false);
        } else {
            // diagonal tile: subtiles > wave are fully masked -> skip
            for (int sub = 0; sub < wave; ++sub) body(sub, false);
            body(wave, true);
        }
        barrier_lds_only();
    }

    // ---- epilogue: full l on every lane, normalize, store fp32 ----
    ls += __shfl_xor(ls, 16);
    ls += __shfl_xor(ls, 32);
#pragma unroll
    for (int r = 0; r < 4; ++r) {
        float lr = __shfl(ls, quad * 4 + r);   // l for output row q0+quad*4+r
        float inv = 1.0f / lr;
        int q = q0 + quad * 4 + r;
        float* ob = out + (((size_t)(b * L_ + q)) * H_ + h) * 64 + lo;
        ob[0]  = o[0][r] * inv;
        ob[16] = o[1][r] * inv;
        ob[32] = o[2][r] * inv;
        ob[48] = o[3][r] * inv;
    }
}

extern "C" void kernel_launch(void* const* d_in, const int* in_sizes, int n_in,
                              void* d_out, int out_size, void* d_ws, size_t ws_size,
                              hipStream_t stream) {
    const float* q = (const float*)d_in[0];
    const float* k = (const float*)d_in[1];
    const float* v = (const float*)d_in[2];
    // d_in[3] = attn_mask: deterministic causal, recomputed analytically.
    float* out = (float*)d_out;

    const size_t TSZ = (size_t)B_ * H_ * L_ * 64;
    u16* qp = (u16*)d_ws;
    u16* kp = qp + TSZ;
    u16* vt = kp + TSZ;

    prep_kernel<<<5120, 256, 0, stream>>>(q, k, v, qp, kp, vt);
    flash_kernel<<<1024, 256, 0, stream>>>(qp, kp, vt, out);
}